// Round 2
// baseline (628.400 us; speedup 1.0000x reference)
//
#include <hip/hip_runtime.h>
#include <hip/hip_bf16.h>
#include <hip/hip_fp16.h>

#define NB 256      // batch
#define NT 1024     // time
#define ND 64       // input dim
#define NH 128      // hidden dim

typedef __fp16 half8 __attribute__((ext_vector_type(8)));
typedef __fp16 half4v __attribute__((ext_vector_type(4)));
typedef __fp16 half2v __attribute__((ext_vector_type(2)));
typedef float float4v __attribute__((ext_vector_type(4)));

static __device__ __forceinline__ float fast_tanh(float v) {
    float e = __expf(2.0f * v);
    return 1.0f - 2.0f * __builtin_amdgcn_rcpf(e + 1.0f);
}

static __device__ __forceinline__ float fdot2f(half2v a, half2v b, float c) {
#if __has_builtin(__builtin_amdgcn_fdot2)
    return __builtin_amdgcn_fdot2(a, b, c, false);
#else
    return c + (float)a.x * (float)b.x + (float)a.y * (float)b.y;
#endif
}

// lgkm-only barrier: does NOT drain vmcnt (global stores / x prefetch keep flying)
static __device__ __forceinline__ void fast_barrier() {
    asm volatile("s_waitcnt lgkmcnt(0)\n\ts_barrier" ::: "memory");
}

static __device__ __forceinline__ float dpp_xor1_add(float x) {
#if __has_builtin(__builtin_amdgcn_mov_dpp)
    int o = __builtin_amdgcn_mov_dpp(__builtin_bit_cast(int, x), 0xB1, 0xF, 0xF, true);
    return x + __builtin_bit_cast(float, o);
#else
    return x + __shfl_xor(x, 1);
#endif
}

static __device__ __forceinline__ float dpp_xor2_add(float x) {
#if __has_builtin(__builtin_amdgcn_mov_dpp)
    int o = __builtin_amdgcn_mov_dpp(__builtin_bit_cast(int, x), 0x4E, 0xF, 0xF, true);
    return x + __builtin_bit_cast(float, o);
#else
    return x + __shfl_xor(x, 2);
#endif
}

// Fused, wave-specialized: 8 recurrence waves (4-way k-split) + 4 projection waves.
// grid 256 (block = batch) x 768 threads.
//   tid <  512 : recurrence. j = tid>>2, kh = tid&3 (32-elem dot slice each).
//   tid >= 512 : projection. Stages x chunk c+1, runs MFMA between step-barriers.
// Barrier discipline: BOTH paths execute exactly 16 fast_barrier() per chunk.
__global__ __launch_bounds__(768) void fused_rnn_kernel(
        const float* __restrict__ x,
        const float* __restrict__ WxK, const float* __restrict__ bxK,
        const float* __restrict__ Wxz, const float* __restrict__ bxz,
        const float* __restrict__ Whk, const float* __restrict__ bhk,
        float* __restrict__ out) {
    __shared__ __align__(16) __fp16 wsm[2][128][72];    // 36 KB: W_xK / W_xz fp16 [h][d]
    __shared__ __align__(16) __fp16 xsm[16][72];        // one x chunk (16 t x 64 d) fp16; proj-owned
    __shared__ __align__(16) __fp16 hbuf[2][128];       // h fp16, dbuf per step
    __shared__ __align__(16) __fp16 gbuf[2][16][132];   // gxK chunk dbuf
    __shared__ __align__(16) __fp16 zbuf[2][16][132];   // z   chunk dbuf

    const int tid = threadIdx.x;
    const int b = blockIdx.x;

    // recurrence ids
    const int j = tid >> 2, kh = tid & 3;
    // projection ids (valid when tid >= 512)
    const int pt = tid & 255;
    const int pwid = pt >> 6, plane = pt & 63;
    const int pl16 = plane & 15, pkg = plane >> 4;

    const float4v* xsrc = (const float4v*)(x + (size_t)b * NT * ND);

    // ---- stage W_xK / W_xz into LDS as fp16 (threads 0..255, once) ----
    if (tid < 256) {
        #pragma unroll
        for (int mat = 0; mat < 2; ++mat) {
            const float* Wsrc = mat ? Wxz : WxK;
            const float4v* ws4 = (const float4v*)(Wsrc + (size_t)(tid >> 1) * 64 + (tid & 1) * 32);
            #pragma unroll
            for (int i = 0; i < 4; ++i) {
                float4v a = ws4[2 * i], c2 = ws4[2 * i + 1];
                half8 hv = {(__fp16)a.x, (__fp16)a.y, (__fp16)a.z, (__fp16)a.w,
                            (__fp16)c2.x, (__fp16)c2.y, (__fp16)c2.z, (__fp16)c2.w};
                *(half8*)&wsm[mat][tid >> 1][(tid & 1) * 32 + i * 8] = hv;
            }
        }
    }

    // per-path persistent state
    half2v w[16];            // rec: W_hK row j, k-quarter kh (32 fp16)
    float bj = 0.0f;
    float hn = 0.0f;
    float oreg[16];
    float4v xg;              // proj: in-flight x chunk
    float bK0 = 0.f, bK1 = 0.f, bz0 = 0.f, bz1 = 0.f;

    if (tid < 512) {
        const float4v* wsrc = (const float4v*)(Whk + (size_t)j * NH + kh * 32);
        #pragma unroll
        for (int i = 0; i < 8; ++i) {
            float4v wv = wsrc[i];
            w[2 * i]     = __builtin_amdgcn_cvt_pkrtz(wv.x, wv.y);
            w[2 * i + 1] = __builtin_amdgcn_cvt_pkrtz(wv.z, wv.w);
        }
        bj = bhk[j];
        if (tid < 128) hbuf[0][tid] = (__fp16)0.0f;   // h0 = 0
    } else {
        xg = xsrc[pt];   // x chunk 0
        const int hc0 = (2 * pwid + 0) * 16 + pl16;
        const int hc1 = (2 * pwid + 1) * 16 + pl16;
        bK0 = bxK[hc0]; bK1 = bxK[hc1];
        bz0 = bxz[hc0]; bz1 = bxz[hc1];
        half4v hx = {(__fp16)xg.x, (__fp16)xg.y, (__fp16)xg.z, (__fp16)xg.w};
        *(half4v*)&xsm[pt >> 4][(pt & 15) * 4] = hx;
    }
    __syncthreads();   // wsm + xsm(chunk0) ready

    // 16x64x128 x2 GEMM on staged chunk; 8 MFMAs per proj wave
    auto proj_mfma = [&](float4v (&pacc)[2][2]) {
        #pragma unroll
        for (int n2 = 0; n2 < 2; ++n2)
            #pragma unroll
            for (int mat = 0; mat < 2; ++mat)
                pacc[n2][mat] = (float4v){0.f, 0.f, 0.f, 0.f};
        #pragma unroll
        for (int ks = 0; ks < 2; ++ks) {
            half8 af = *(const half8*)&xsm[pl16][ks * 32 + pkg * 8];
            #pragma unroll
            for (int n2 = 0; n2 < 2; ++n2) {
                const int nt = 2 * pwid + n2;
                #pragma unroll
                for (int mat = 0; mat < 2; ++mat) {
                    half8 bf = *(const half8*)&wsm[mat][nt * 16 + pl16][ks * 32 + pkg * 8];
                    pacc[n2][mat] =
                        __builtin_amdgcn_mfma_f32_16x16x32_f16(af, bf, pacc[n2][mat], 0, 0, 0);
                }
            }
        }
    };
    auto proj_epilogue = [&](float4v (&pacc)[2][2], int dst) {
        #pragma unroll
        for (int n2 = 0; n2 < 2; ++n2) {
            const int col = (2 * pwid + n2) * 16 + pl16;
            const float bK = n2 ? bK1 : bK0;
            const float bz = n2 ? bz1 : bz0;
            #pragma unroll
            for (int r = 0; r < 4; ++r) {
                const int row = pkg * 4 + r;
                gbuf[dst][row][col] = (__fp16)(pacc[n2][0][r] + bK);
                zbuf[dst][row][col] = (__fp16)fast_tanh(pacc[n2][1][r] + bz);
            }
        }
    };

    // project chunk 0 into buf 0; kick off load of chunk 1
    if (tid >= 512) {
        float4v pacc[2][2];
        proj_mfma(pacc);
        proj_epilogue(pacc, 0);
        xg = xsrc[256 + pt];
    }
    __syncthreads();   // gbuf/zbuf[0] ready

    const size_t obase = (size_t)(kh & 1) * ((size_t)NB * NT * NH)
                       + (size_t)b * NT * NH + j;
    const int sh = (kh >> 1) * 8;   // which 8 timesteps of the chunk this thread stores

    for (int c = 0; c < 64; ++c) {
        const int cb = c & 1;

        if (tid < 512) {
            // ---------------- recurrence waves: clean 16-step loop ----------------
            float gxv[16], zvv[16];
            #pragma unroll
            for (int s = 0; s < 16; ++s) {
                gxv[s] = (float)gbuf[cb][s][j] + bj;
                zvv[s] = (float)zbuf[cb][s][j];
            }

            #pragma unroll
            for (int s = 0; s < 16; ++s) {
                const int t = c * 16 + s;
                const half8* hs = (const half8*)&hbuf[t & 1][kh * 32];
                float a0 = 0.f, a1 = 0.f, a2 = 0.f, a3 = 0.f;
                #pragma unroll
                for (int i = 0; i < 4; ++i) {
                    half8 hv = hs[i];
                    a0 = fdot2f(w[4 * i + 0], __builtin_shufflevector(hv, hv, 0, 1), a0);
                    a1 = fdot2f(w[4 * i + 1], __builtin_shufflevector(hv, hv, 2, 3), a1);
                    a2 = fdot2f(w[4 * i + 2], __builtin_shufflevector(hv, hv, 4, 5), a2);
                    a3 = fdot2f(w[4 * i + 3], __builtin_shufflevector(hv, hv, 6, 7), a3);
                }
                const float acc = (a0 + a1) + (a2 + a3);
                const float gh = dpp_xor2_add(dpp_xor1_add(acc));   // sum over 4 k-quarters

                const float d = zvv[s] - hn;
                const float pre = gh + gxv[s];
                const float Kg = __builtin_amdgcn_rcpf(1.0f + __expf(-pre));
                const float v = __builtin_fmaf(Kg, d, hn);
                hn = fast_tanh(v);
                oreg[s] = hn;

                if (kh == 0) hbuf[(t + 1) & 1][j] = (__fp16)hn;

                fast_barrier();                              // step barrier (1 of 16)
            }

            // flush this thread's 8 outputs (copy = kh&1, s-half = kh>>1)
            #pragma unroll
            for (int i = 0; i < 8; ++i)
                out[obase + (size_t)(c * 16 + sh + i) * NH] = oreg[sh + i];
        } else {
            // ---------------- projection waves ----------------
            if (c + 1 < 64) {
                // xg holds x chunk c+1 (loaded one chunk ago; vmcnt long satisfied)
                half4v hx = {(__fp16)xg.x, (__fp16)xg.y, (__fp16)xg.z, (__fp16)xg.w};
                *(half4v*)&xsm[pt >> 4][(pt & 15) * 4] = hx;
                fast_barrier();                              // barrier 1: xsm visible
                float4v pacc[2][2];
                proj_mfma(pacc);
                proj_epilogue(pacc, cb ^ 1);                 // next chunk's buffers
                if (c + 2 < 64) xg = xsrc[(size_t)(c + 2) * 256 + pt];
                #pragma unroll
                for (int k = 0; k < 15; ++k) fast_barrier(); // barriers 2..16
            } else {
                #pragma unroll
                for (int k = 0; k < 16; ++k) fast_barrier(); // last chunk: idle sync
            }
        }
    }
}

extern "C" void kernel_launch(void* const* d_in, const int* in_sizes, int n_in,
                              void* d_out, int out_size, void* d_ws, size_t ws_size,
                              hipStream_t stream) {
    (void)in_sizes; (void)n_in; (void)d_ws; (void)ws_size; (void)out_size;
    const float* x   = (const float*)d_in[0];
    const float* WxK = (const float*)d_in[1];
    const float* bxK = (const float*)d_in[2];
    const float* Wxz = (const float*)d_in[3];
    const float* bxz = (const float*)d_in[4];
    const float* Whk = (const float*)d_in[5];
    const float* bhk = (const float*)d_in[6];
    float* out = (float*)d_out;

    fused_rnn_kernel<<<256, 768, 0, stream>>>(x, WxK, bxK, Wxz, bxz, Whk, bhk, out);
}